// Round 5
// baseline (1098.485 us; speedup 1.0000x reference)
//
#include <hip/hip_runtime.h>
#include <cstdint>
#include <cstddef>

#define SEQ 8192
#define THREADS 256
#define THR_F 200.0f
#define EPS_F 1e-7f

// Workspace accumulator layout (doubles):
// 0 err2, 1 msum, 2 bce(base+corr), 3 wExtra, 4 mono, 5 vp, 6 smooth, 7 vt,
// 8 phys, 9 npos, 10 bound, 11 any1
#define N_ACC 12

// LDS: 32KB s_pred + 8KB s_mask + small -> 40.3 KiB => 3 blocks/CU max.
// __launch_bounds__ 2nd arg is min waves per EU: 3 waves/EU * 4 EU / 4 waves-per-block = 3 blocks/CU.
__global__ __launch_bounds__(THREADS, 3) void physloss_row_kernel(
    const float* __restrict__ pred,
    const float* __restrict__ targ,
    const float* __restrict__ bprob,
    const int*   __restrict__ mask,
    const float* __restrict__ voltage,
    const float* __restrict__ thickness,
    double* __restrict__ acc)
{
    __shared__ float s_pred[SEQ];
    __shared__ unsigned char s_mask[SEQ];
    __shared__ float red[4][10];
    __shared__ int redLast[4];

    const int row = blockIdx.x;
    const int t = threadIdx.x;
    const size_t base = (size_t)row * SEQ;

    const float4* p4 = (const float4*)(pred + base);
    const float4* t4 = (const float4*)(targ + base);
    const float4* b4 = (const float4*)(bprob + base);
    const int4*   m4 = (const int4*)(mask + base);

    float err2 = 0.f, msum = 0.f, bce = 0.f, bound = 0.f;
    int lastIdx = -1;

    // ---- Phase 1: coalesced streaming load + element-local terms + LDS stage ----
    #pragma unroll
    for (int j = 0; j < SEQ / 4 / THREADS; ++j) {
        int i4 = t + j * THREADS;
        float4 p  = p4[i4];
        float4 tv = t4[i4];
        float4 bv = b4[i4];
        int4   mv = m4[i4];

        ((float4*)s_pred)[i4] = p;
        uchar4 mb;
        mb.x = mv.x ? 1 : 0; mb.y = mv.y ? 1 : 0;
        mb.z = mv.z ? 1 : 0; mb.w = mv.w ? 1 : 0;
        ((uchar4*)s_mask)[i4] = mb;

        float pe[4] = {p.x, p.y, p.z, p.w};
        float te[4] = {tv.x, tv.y, tv.z, tv.w};
        float be[4] = {bv.x, bv.y, bv.z, bv.w};
        int   me[4] = {mv.x, mv.y, mv.z, mv.w};

        #pragma unroll
        for (int e = 0; e < 4; ++e) {
            float m = me[e] ? 1.f : 0.f;
            float d = pe[e] - te[e];
            err2 += d * d * m;
            msum += m;
            bound += fmaxf(pe[e] - THR_F, 0.f);
            float pc = fminf(fmaxf(be[e], EPS_F), 1.0f - EPS_F);
            bce += m * (-log1pf(-pc));
            if (me[e]) lastIdx = 4 * i4 + e;   // indices strictly increase with j,e
        }
    }

    __syncthreads();

    // ---- Phase 2: neighbor terms from LDS (stride-256 interleave: conflict-free) ----
    float mono = 0.f, vp = 0.f, smooth = 0.f, vt = 0.f, vdiff = 0.f, mfirst = 0.f;
    #pragma unroll
    for (int j = 0; j < SEQ / THREADS; ++j) {
        int i = t + j * THREADS;
        float p0 = s_pred[i];
        float m0 = s_mask[i] ? 1.f : 0.f;
        if (i < SEQ - 1) {
            float p1 = s_pred[i + 1];
            float m1 = s_mask[i + 1] ? 1.f : 0.f;
            float d = p1 - p0;
            float mm = m0 * m1;
            mono += fmaxf(-d, 0.f) * mm;
            vp += mm;
            vdiff += d * m0;
            mfirst += m0;
            if (i < SEQ - 2) {
                float p2 = s_pred[i + 2];
                float m2 = s_mask[i + 2] ? 1.f : 0.f;
                float t3 = mm * m2;
                smooth += fabsf(p2 - 2.f * p1 + p0) * t3;
                vt += t3;
            }
        }
    }

    // ---- Wave reduce (64-lane) then cross-wave via LDS ----
    float v[10] = {err2, msum, bce, bound, mono, vp, smooth, vt, vdiff, mfirst};
    #pragma unroll
    for (int off = 32; off > 0; off >>= 1) {
        #pragma unroll
        for (int k = 0; k < 10; ++k) v[k] += __shfl_down(v[k], off, 64);
        int o = __shfl_down(lastIdx, off, 64);
        lastIdx = lastIdx > o ? lastIdx : o;
    }
    int wave = t >> 6, lane = t & 63;
    if (lane == 0) {
        #pragma unroll
        for (int k = 0; k < 10; ++k) red[wave][k] = v[k];
        redLast[wave] = lastIdx;
    }
    __syncthreads();

    if (t == 0) {
        float s[10];
        #pragma unroll
        for (int k = 0; k < 10; ++k) s[k] = red[0][k] + red[1][k] + red[2][k] + red[3][k];
        int last = redLast[0];
        #pragma unroll
        for (int w = 1; w < 4; ++w) last = last > redLast[w] ? last : redLast[w];

        // breakdown-target correction at the last valid index
        float bceCorr = 0.f, wExtra = 0.f;
        if (last >= 0) {
            float tl = targ[base + last];
            bool cond = (last < SEQ - 1) || (tl >= 190.0f);  // THR*0.95 == 190.0f in f32
            if (cond) {
                float pl = fminf(fmaxf(bprob[base + last], EPS_F), 1.0f - EPS_F);
                // base already added -log1p(-pl)*1 (mask=1 at last); replace with 5*(-log(pl))
                bceCorr = -5.0f * logf(pl) + log1pf(-pl);
                wExtra = 4.0f;
            }
        }

        float m0row = s_mask[0] ? 1.f : 0.f;
        float any1 = (s[1] - m0row) > 0.f ? 1.f : 0.f;  // any valid in cols 1..S-1

        // physics per-row term
        float physv = 0.f, nposv = 0.f;
        float avg = s[8] / fmaxf(s[9], 1.f);
        if (avg > 0.f) {
            float lr = logf(fmaxf(avg, 1e-8f));
            float ef = fabsf(voltage[row]) / thickness[row] * 1e-7f;
            float ff = expf(0.1f * ef);
            float lff = logf(fmaxf(ff, 1e-8f));
            float dd = lr - lff;
            physv = dd * dd;
            nposv = 1.f;
        }

        atomicAdd(&acc[0],  (double)s[0]);            // err2
        atomicAdd(&acc[1],  (double)s[1]);            // msum
        atomicAdd(&acc[2],  (double)(s[2] + bceCorr));// bce
        atomicAdd(&acc[3],  (double)wExtra);          // extra weight (4 per bt row)
        atomicAdd(&acc[4],  (double)s[4]);            // mono
        atomicAdd(&acc[5],  (double)s[5]);            // vp
        atomicAdd(&acc[6],  (double)s[6]);            // smooth
        atomicAdd(&acc[7],  (double)s[7]);            // vt
        atomicAdd(&acc[8],  (double)physv);           // phys
        atomicAdd(&acc[9],  (double)nposv);           // npos
        atomicAdd(&acc[10], (double)s[3]);            // bound
        atomicAdd(&acc[11], (double)any1);            // any1
    }
}

__global__ void physloss_finalize_kernel(const double* __restrict__ acc,
                                         float* __restrict__ out,
                                         double inv_count_scale /* = 1/(B*S) */)
{
    if (threadIdx.x == 0 && blockIdx.x == 0) {
        double err2 = acc[0], msum = acc[1], bce = acc[2], wX = acc[3];
        double mono = acc[4], vp = acc[5], sm = acc[6], vt = acc[7];
        double ph = acc[8], np = acc[9], bd = acc[10], a1 = acc[11];

        bool any = msum > 0.0;
        float predL = any ? (float)(err2 / fmax(msum, 1.0)) : 0.f;
        double wsum = msum + wX;
        float bdL = any ? (float)(bce / fmax(wsum, 1.0)) : 0.f;
        float monoL = (vp > 0.0) ? (float)(mono / fmax(vp, 1.0)) : 0.f;
        float smL = (vt > 0.0) ? (float)(sm / fmax(vt, 1.0)) : 0.f;
        float phL = (a1 > 0.0 && np > 0.0) ? (float)(ph / fmax(np, 1.0)) : 0.f;
        float boL = (float)(bd * inv_count_scale) * 0.1f;

        float total = 1.0f * predL + 0.5f * bdL + 0.2f * monoL
                    + 0.1f * smL + 0.3f * phL + boL;

        out[0] = predL; out[1] = bdL; out[2] = monoL; out[3] = smL;
        out[4] = phL;   out[5] = boL; out[6] = total;
    }
}

extern "C" void kernel_launch(void* const* d_in, const int* in_sizes, int n_in,
                              void* d_out, int out_size, void* d_ws, size_t ws_size,
                              hipStream_t stream) {
    const float* pred  = (const float*)d_in[0];
    const float* targ  = (const float*)d_in[1];
    const float* bprob = (const float*)d_in[2];
    const int*   mask  = (const int*)d_in[3];    // bool -> int32 per harness dtype rules
    const float* volt  = (const float*)d_in[4];
    const float* thick = (const float*)d_in[5];

    const int B = in_sizes[4];                   // voltage is [B]
    double* acc = (double*)d_ws;

    hipMemsetAsync(acc, 0, N_ACC * sizeof(double), stream);
    physloss_row_kernel<<<B, THREADS, 0, stream>>>(pred, targ, bprob, mask,
                                                   volt, thick, acc);
    double inv_cnt = 1.0 / ((double)B * (double)SEQ);
    physloss_finalize_kernel<<<1, 64, 0, stream>>>(acc, (float*)d_out, inv_cnt);
}